// Round 10
// baseline (297.086 us; speedup 1.0000x reference)
//
#include <hip/hip_runtime.h>
#include <hip/hip_bf16.h>

#define N 20000
#define E 200000
#define IN 128
#define OUT 128
#define NB 8
#define SI 16
#define SO 16
#define R 230
#define T 365

// All scratch in module .bss — d_ws untouched, no runtime API calls in
// kernel_launch (graph-capture-proven structure from R9).
__device__ float g_agg[(size_t)N * OUT];        // 10.24 MB agg result
__device__ int   g_deg[N];                      // in-degree
__device__ int   g_off[N + 1];                  // CSR row offsets
__device__ int   g_cur[N];                      // scatter cursors
__device__ int   g_srt_src[E];                  // dst-sorted edge sources
__device__ int   g_srt_typ[E];                  // dst-sorted edge types
__device__ float g_srt_nrm[E];                  // dst-sorted edge norms
__device__ float g_wt[(size_t)R * NB * SI * SO]; // weight^T: [r][b][ol][i]

__global__ void zero_deg_kernel() {
    int i = blockIdx.x * blockDim.x + threadIdx.x;
    if (i < N) g_deg[i] = 0;
}

// weight[r][b][i][ol] -> g_wt[r][b][ol][i] (1.88 MB, coalesced reads)
__global__ void transpose_w_kernel(const float* __restrict__ weight) {
    int k = blockIdx.x * blockDim.x + threadIdx.x;
    if (k >= R * NB * SI * SO) return;
    int r    = k >> 11;          // /2048
    int rem  = k & 2047;
    int b    = rem >> 8;         // /256
    int rem2 = rem & 255;
    int i    = rem2 >> 4;
    int ol   = rem2 & 15;
    g_wt[(long)r * 2048 + b * 256 + ol * 16 + i] = weight[k];
}

__global__ void count_kernel(const int* __restrict__ edge_dst) {
    int e = blockIdx.x * blockDim.x + threadIdx.x;
    if (e < E) atomicAdd(&g_deg[edge_dst[e]], 1);
}

// Single-block exclusive prefix sum over g_deg (N=20000), 1024 threads,
// chunk=20 each; Hillis-Steele inclusive scan of the 1024 chunk sums in LDS.
__global__ __launch_bounds__(1024) void scan_kernel() {
    __shared__ int part[1024];
    const int t = threadIdx.x;
    const int base = t * 20;
    int csum = 0;
    int d[20];
#pragma unroll
    for (int k = 0; k < 20; ++k) {
        int idx = base + k;
        d[k] = (idx < N) ? g_deg[idx] : 0;
        csum += d[k];
    }
    part[t] = csum;
    __syncthreads();
    for (int off = 1; off < 1024; off <<= 1) {
        int v = (t >= off) ? part[t - off] : 0;
        __syncthreads();
        part[t] += v;
        __syncthreads();
    }
    int run = part[t] - csum;   // exclusive prefix of this chunk
#pragma unroll
    for (int k = 0; k < 20; ++k) {
        int idx = base + k;
        if (idx < N) {
            g_off[idx] = run;
            g_cur[idx] = run;
            run += d[k];
        }
    }
    if (t == 1023) g_off[N] = part[1023];   // == E
}

// Bucket edges by destination into SoA (src, type, norm).
__global__ void scatter_kernel(const int* __restrict__ edge_src,
                               const int* __restrict__ edge_dst,
                               const int* __restrict__ edge_type,
                               const float* __restrict__ edge_norm) {
    int e = blockIdx.x * blockDim.x + threadIdx.x;
    if (e >= E) return;
    int dnode = edge_dst[e];
    int pos = atomicAdd(&g_cur[dnode], 1);
    g_srt_src[pos] = edge_src[e];
    g_srt_typ[pos] = edge_type[e];
    g_srt_nrm[pos] = edge_norm[e];
}

// Node-centric message aggregation: block per node, thread per out feature.
// Recomputes each incoming edge's message in registers; ZERO float atomics,
// one coalesced store per (node, feature).
__global__ __launch_bounds__(128) void agg_kernel(const float* __restrict__ h) {
    const int n   = blockIdx.x;
    const int tid = threadIdx.x;     // out feature o
    const int b   = tid >> 4;
    const int ol  = tid & 15;
    const int j0 = g_off[n], j1 = g_off[n + 1];
    float acc = 0.f;
    for (int j = j0; j < j1; ++j) {
        int   s  = g_srt_src[j];     // same addr across block -> broadcast
        int   r  = g_srt_typ[j];
        float nr = g_srt_nrm[j];
        const float4* hp = reinterpret_cast<const float4*>(h + (long)s * IN + b * SI);
        const float4* wp = reinterpret_cast<const float4*>(g_wt + (long)r * 2048 + b * 256 + ol * SI);
        float dot = 0.f;
#pragma unroll
        for (int q = 0; q < 4; ++q) {
            float4 a = hp[q];
            float4 w = wp[q];
            dot = fmaf(a.x, w.x, dot);
            dot = fmaf(a.y, w.y, dot);
            dot = fmaf(a.z, w.z, dot);
            dot = fmaf(a.w, w.w, dot);
        }
        acc = fmaf(dot, nr, acc);
    }
    g_agg[(long)n * OUT + tid] = acc;
}

// 16 nodes per block, 128 threads (thread = out feature). Unchanged from R9.
__global__ __launch_bounds__(128) void node_kernel(
        const float* __restrict__ h,
        const float* __restrict__ node_norm,
        const float* __restrict__ h_bias,
        const float* __restrict__ loop_weight,
        const float* __restrict__ time_embed,
        const int* __restrict__ time_idx,
        float* __restrict__ out) {
    __shared__ float hsm[IN * 16];   // hsm[i*16 + nl]
    const int tid  = threadIdx.x;
    const int base = blockIdx.x * 16;

    for (int k = tid; k < 16 * IN; k += 128) {
        int nl = k >> 7;
        int i  = k & 127;
        hsm[i * 16 + nl] = h[(long)(base + nl) * IN + i];
    }
    __syncthreads();

    float acc[16];
#pragma unroll
    for (int nl = 0; nl < 16; ++nl) acc[nl] = 0.f;

    for (int i = 0; i < IN; ++i) {
        float w = loop_weight[(long)i * OUT + tid];
        const float4* hp = reinterpret_cast<const float4*>(&hsm[i * 16]);
#pragma unroll
        for (int q = 0; q < 4; ++q) {
            float4 hv = hp[q];
            acc[q * 4 + 0] = fmaf(hv.x, w, acc[q * 4 + 0]);
            acc[q * 4 + 1] = fmaf(hv.y, w, acc[q * 4 + 1]);
            acc[q * 4 + 2] = fmaf(hv.z, w, acc[q * 4 + 2]);
            acc[q * 4 + 3] = fmaf(hv.w, w, acc[q * 4 + 3]);
        }
    }

    float bias = h_bias[tid];
#pragma unroll
    for (int nl = 0; nl < 16; ++nl) {
        int n = base + nl;
        float v = g_agg[(long)n * OUT + tid] * node_norm[n] + bias + acc[nl];
        out[(long)n * OUT + tid] = fmaxf(v, 0.f);
        out[(long)N * OUT + (long)n * IN + tid] =
            time_embed[(long)time_idx[n] * IN + tid];
    }
}

extern "C" void kernel_launch(void* const* d_in, const int* in_sizes, int n_in,
                              void* d_out, int out_size, void* d_ws, size_t ws_size,
                              hipStream_t stream) {
    const float* h           = (const float*)d_in[0];
    const float* edge_norm   = (const float*)d_in[1];
    const float* node_norm   = (const float*)d_in[2];
    const float* weight      = (const float*)d_in[3];
    const float* h_bias      = (const float*)d_in[4];
    const float* loop_weight = (const float*)d_in[5];
    const float* time_embed  = (const float*)d_in[6];
    const int*   edge_src    = (const int*)d_in[7];
    const int*   edge_dst    = (const int*)d_in[8];
    const int*   edge_type   = (const int*)d_in[9];
    const int*   time_idx    = (const int*)d_in[10];
    float* out = (float*)d_out;

    zero_deg_kernel<<<(N + 255) / 256, 256, 0, stream>>>();
    transpose_w_kernel<<<(R * NB * SI * SO + 255) / 256, 256, 0, stream>>>(weight);
    count_kernel<<<(E + 255) / 256, 256, 0, stream>>>(edge_dst);
    scan_kernel<<<1, 1024, 0, stream>>>();
    scatter_kernel<<<(E + 255) / 256, 256, 0, stream>>>(
        edge_src, edge_dst, edge_type, edge_norm);
    agg_kernel<<<N, 128, 0, stream>>>(h);
    node_kernel<<<N / 16, 128, 0, stream>>>(
        h, node_norm, h_bias, loop_weight, time_embed, time_idx, out);
}

// Round 11
// 294.253 us; speedup vs baseline: 1.0096x; 1.0096x over previous
//
#include <hip/hip_runtime.h>
#include <hip/hip_bf16.h>

#define N 20000
#define E 200000
#define IN 128
#define OUT 128
#define NB 8
#define SI 16
#define SO 16
#define R 230
#define T 365

// All scratch in module .bss — d_ws untouched, no runtime API calls in
// kernel_launch (graph-capture-proven structure).
__device__ float g_msg[(size_t)E * OUT];   // 102.4 MB materialized messages
__device__ float g_agg[(size_t)N * OUT];   // 10.24 MB aggregated messages
__device__ int   g_deg[N];                 // in-degree
__device__ int   g_off[N + 1];             // CSR row offsets
__device__ int   g_cur[N];                 // scatter cursors
__device__ int   g_eid[E];                 // dst-sorted original edge ids

__global__ void zero_deg_kernel() {
    int i = blockIdx.x * blockDim.x + threadIdx.x;
    if (i < N) g_deg[i] = 0;
}

__global__ void count_kernel(const int* __restrict__ edge_dst) {
    int e = blockIdx.x * blockDim.x + threadIdx.x;
    if (e < E) atomicAdd(&g_deg[edge_dst[e]], 1);
}

// Single-block exclusive prefix sum over g_deg (N=20000).
__global__ __launch_bounds__(1024) void scan_kernel() {
    __shared__ int part[1024];
    const int t = threadIdx.x;
    const int base = t * 20;
    int csum = 0;
    int d[20];
#pragma unroll
    for (int k = 0; k < 20; ++k) {
        int idx = base + k;
        d[k] = (idx < N) ? g_deg[idx] : 0;
        csum += d[k];
    }
    part[t] = csum;
    __syncthreads();
    for (int off = 1; off < 1024; off <<= 1) {
        int v = (t >= off) ? part[t - off] : 0;
        __syncthreads();
        part[t] += v;
        __syncthreads();
    }
    int run = part[t] - csum;
#pragma unroll
    for (int k = 0; k < 20; ++k) {
        int idx = base + k;
        if (idx < N) {
            g_off[idx] = run;
            g_cur[idx] = run;
            run += d[k];
        }
    }
    if (t == 1023) g_off[N] = part[1023];
}

// Bucket original edge ids by destination.
__global__ void scatter_kernel(const int* __restrict__ edge_dst) {
    int e = blockIdx.x * blockDim.x + threadIdx.x;
    if (e >= E) return;
    int pos = atomicAdd(&g_cur[edge_dst[e]], 1);
    g_eid[pos] = e;
}

// One thread per (edge, out_feature) — R9's proven loop, atomic replaced by
// a plain coalesced store into g_msg[e*128+o].
__global__ void msg_kernel(const float* __restrict__ h,
                           const float* __restrict__ edge_norm,
                           const float* __restrict__ weight,
                           const int* __restrict__ edge_src,
                           const int* __restrict__ edge_type) {
    long idx = (long)blockIdx.x * blockDim.x + threadIdx.x;
    int e = (int)(idx >> 7);
    if (e >= E) return;
    int o  = (int)(idx & 127);
    int b  = o >> 4;
    int ol = o & 15;
    int s = edge_src[e];
    int r = edge_type[e];
    const float* src = h + (long)s * IN + b * SI;
    const float* W   = weight + (long)r * (NB * SI * SO) + b * (SI * SO) + ol;
    float acc = 0.f;
#pragma unroll
    for (int i = 0; i < SI; ++i)
        acc = fmaf(src[i], W[i * SO], acc);
    g_msg[idx] = acc * edge_norm[e];
}

// CSR aggregation: block per node, thread per out feature, 4 independent
// message-row loads in flight (breaks the serial latency chain of R10).
__global__ __launch_bounds__(128) void agg_kernel() {
    const int n   = blockIdx.x;
    const int tid = threadIdx.x;
    const int j0 = g_off[n], j1 = g_off[n + 1];
    float acc = 0.f;
    int j = j0;
    for (; j + 4 <= j1; j += 4) {
        int e0 = g_eid[j], e1 = g_eid[j + 1], e2 = g_eid[j + 2], e3 = g_eid[j + 3];
        float v0 = g_msg[(long)e0 * OUT + tid];
        float v1 = g_msg[(long)e1 * OUT + tid];
        float v2 = g_msg[(long)e2 * OUT + tid];
        float v3 = g_msg[(long)e3 * OUT + tid];
        acc += (v0 + v1) + (v2 + v3);
    }
    for (; j < j1; ++j)
        acc += g_msg[(long)g_eid[j] * OUT + tid];
    g_agg[(long)n * OUT + tid] = acc;
}

// 16 nodes per block, 128 threads (thread = out feature). Unchanged.
__global__ __launch_bounds__(128) void node_kernel(
        const float* __restrict__ h,
        const float* __restrict__ node_norm,
        const float* __restrict__ h_bias,
        const float* __restrict__ loop_weight,
        const float* __restrict__ time_embed,
        const int* __restrict__ time_idx,
        float* __restrict__ out) {
    __shared__ float hsm[IN * 16];   // hsm[i*16 + nl]
    const int tid  = threadIdx.x;
    const int base = blockIdx.x * 16;

    for (int k = tid; k < 16 * IN; k += 128) {
        int nl = k >> 7;
        int i  = k & 127;
        hsm[i * 16 + nl] = h[(long)(base + nl) * IN + i];
    }
    __syncthreads();

    float acc[16];
#pragma unroll
    for (int nl = 0; nl < 16; ++nl) acc[nl] = 0.f;

    for (int i = 0; i < IN; ++i) {
        float w = loop_weight[(long)i * OUT + tid];
        const float4* hp = reinterpret_cast<const float4*>(&hsm[i * 16]);
#pragma unroll
        for (int q = 0; q < 4; ++q) {
            float4 hv = hp[q];
            acc[q * 4 + 0] = fmaf(hv.x, w, acc[q * 4 + 0]);
            acc[q * 4 + 1] = fmaf(hv.y, w, acc[q * 4 + 1]);
            acc[q * 4 + 2] = fmaf(hv.z, w, acc[q * 4 + 2]);
            acc[q * 4 + 3] = fmaf(hv.w, w, acc[q * 4 + 3]);
        }
    }

    float bias = h_bias[tid];
#pragma unroll
    for (int nl = 0; nl < 16; ++nl) {
        int n = base + nl;
        float v = g_agg[(long)n * OUT + tid] * node_norm[n] + bias + acc[nl];
        out[(long)n * OUT + tid] = fmaxf(v, 0.f);
        out[(long)N * OUT + (long)n * IN + tid] =
            time_embed[(long)time_idx[n] * IN + tid];
    }
}

extern "C" void kernel_launch(void* const* d_in, const int* in_sizes, int n_in,
                              void* d_out, int out_size, void* d_ws, size_t ws_size,
                              hipStream_t stream) {
    const float* h           = (const float*)d_in[0];
    const float* edge_norm   = (const float*)d_in[1];
    const float* node_norm   = (const float*)d_in[2];
    const float* weight      = (const float*)d_in[3];
    const float* h_bias      = (const float*)d_in[4];
    const float* loop_weight = (const float*)d_in[5];
    const float* time_embed  = (const float*)d_in[6];
    const int*   edge_src    = (const int*)d_in[7];
    const int*   edge_dst    = (const int*)d_in[8];
    const int*   edge_type   = (const int*)d_in[9];
    const int*   time_idx    = (const int*)d_in[10];
    float* out = (float*)d_out;

    zero_deg_kernel<<<(N + 255) / 256, 256, 0, stream>>>();
    count_kernel<<<(E + 255) / 256, 256, 0, stream>>>(edge_dst);
    scan_kernel<<<1, 1024, 0, stream>>>();
    scatter_kernel<<<(E + 255) / 256, 256, 0, stream>>>(edge_dst);

    const long total = (long)E * 128;
    msg_kernel<<<(int)((total + 255) / 256), 256, 0, stream>>>(
        h, edge_norm, weight, edge_src, edge_type);

    agg_kernel<<<N, 128, 0, stream>>>();

    node_kernel<<<N / 16, 128, 0, stream>>>(
        h, node_norm, h_bias, loop_weight, time_embed, time_idx, out);
}

// Round 12
// 242.083 us; speedup vs baseline: 1.2272x; 1.2155x over previous
//
#include <hip/hip_runtime.h>
#include <hip/hip_bf16.h>

#define N 20000
#define E 200000
#define IN 128
#define OUT 128
#define NB 8
#define SI 16
#define SO 16
#define R 230
#define T 365

// All scratch in module .bss (~12 MB) — d_ws untouched, no runtime API calls
// in kernel_launch (graph-capture-proven structure).
__device__ float g_agg[(size_t)N * OUT];   // aggregated messages
__device__ int   g_deg[N];
__device__ int   g_off[N + 1];             // CSR row offsets
__device__ int   g_cur[N];
__device__ int   g_srt_src[E];             // dst-sorted edge sources
__device__ int   g_srt_typ[E];             // dst-sorted edge types
__device__ float g_srt_nrm[E];             // dst-sorted edge norms

__global__ void zero_deg_kernel() {
    int i = blockIdx.x * blockDim.x + threadIdx.x;
    if (i < N) g_deg[i] = 0;
}

__global__ void count_kernel(const int* __restrict__ edge_dst) {
    int e = blockIdx.x * blockDim.x + threadIdx.x;
    if (e < E) atomicAdd(&g_deg[edge_dst[e]], 1);
}

// Single-block exclusive prefix sum over g_deg (N=20000).
__global__ __launch_bounds__(1024) void scan_kernel() {
    __shared__ int part[1024];
    const int t = threadIdx.x;
    const int base = t * 20;
    int csum = 0;
    int d[20];
#pragma unroll
    for (int k = 0; k < 20; ++k) {
        int idx = base + k;
        d[k] = (idx < N) ? g_deg[idx] : 0;
        csum += d[k];
    }
    part[t] = csum;
    __syncthreads();
    for (int off = 1; off < 1024; off <<= 1) {
        int v = (t >= off) ? part[t - off] : 0;
        __syncthreads();
        part[t] += v;
        __syncthreads();
    }
    int run = part[t] - csum;
#pragma unroll
    for (int k = 0; k < 20; ++k) {
        int idx = base + k;
        if (idx < N) {
            g_off[idx] = run;
            g_cur[idx] = run;
            run += d[k];
        }
    }
    if (t == 1023) g_off[N] = part[1023];
}

__global__ void scatter_kernel(const int* __restrict__ edge_src,
                               const int* __restrict__ edge_dst,
                               const int* __restrict__ edge_type,
                               const float* __restrict__ edge_norm) {
    int e = blockIdx.x * blockDim.x + threadIdx.x;
    if (e >= E) return;
    int pos = atomicAdd(&g_cur[edge_dst[e]], 1);
    g_srt_src[pos] = edge_src[e];
    g_srt_typ[pos] = edge_type[e];
    g_srt_nrm[pos] = edge_norm[e];
}

// Fused message+aggregation, node-centric, no atomics, no materialization.
// Block = 1 node, 128 threads = 4 edge-lanes x 32 slots.
// Slot = (b, ol0): thread computes outputs b*16 + ol0..ol0+3 via float4 math.
// W kept in ORIGINAL [r][b][i][ol] layout: per i, 4 consecutive lanes read
// 16B-contiguous, 64B per b-group (the R10 transpose mistake is avoided).
__global__ __launch_bounds__(128) void agg_kernel(const float* __restrict__ h,
                                                  const float* __restrict__ weight) {
    const int n    = blockIdx.x;
    const int tid  = threadIdx.x;
    const int el   = tid >> 5;         // edge lane 0..3
    const int slot = tid & 31;
    const int b    = slot >> 2;
    const int ol0  = (slot & 3) << 2;  // 0,4,8,12
    const int j0 = g_off[n], j1 = g_off[n + 1];

    float4 acc = make_float4(0.f, 0.f, 0.f, 0.f);
    for (int j = j0 + el; j < j1; j += 4) {
        int   s  = g_srt_src[j];
        int   r  = g_srt_typ[j];
        float nr = g_srt_nrm[j];
        const float4* hp = reinterpret_cast<const float4*>(h + (long)s * IN + b * SI);
        const float4* wp = reinterpret_cast<const float4*>(
            weight + (long)r * (NB * SI * SO) + b * (SI * SO) + ol0);
        float4 d = make_float4(0.f, 0.f, 0.f, 0.f);
#pragma unroll
        for (int q = 0; q < 4; ++q) {
            float4 hq = hp[q];
            float4 w0 = wp[(4 * q + 0) * 4];   // row i=4q+0, cols ol0..ol0+3
            float4 w1 = wp[(4 * q + 1) * 4];
            float4 w2 = wp[(4 * q + 2) * 4];
            float4 w3 = wp[(4 * q + 3) * 4];
            d.x = fmaf(hq.x, w0.x, d.x); d.y = fmaf(hq.x, w0.y, d.y);
            d.z = fmaf(hq.x, w0.z, d.z); d.w = fmaf(hq.x, w0.w, d.w);
            d.x = fmaf(hq.y, w1.x, d.x); d.y = fmaf(hq.y, w1.y, d.y);
            d.z = fmaf(hq.y, w1.z, d.z); d.w = fmaf(hq.y, w1.w, d.w);
            d.x = fmaf(hq.z, w2.x, d.x); d.y = fmaf(hq.z, w2.y, d.y);
            d.z = fmaf(hq.z, w2.z, d.z); d.w = fmaf(hq.z, w2.w, d.w);
            d.x = fmaf(hq.w, w3.x, d.x); d.y = fmaf(hq.w, w3.y, d.y);
            d.z = fmaf(hq.w, w3.z, d.z); d.w = fmaf(hq.w, w3.w, d.w);
        }
        acc.x = fmaf(d.x, nr, acc.x);
        acc.y = fmaf(d.y, nr, acc.y);
        acc.z = fmaf(d.z, nr, acc.z);
        acc.w = fmaf(d.w, nr, acc.w);
    }

    // Reduce the 4 edge-lanes in LDS, then one coalesced float4 store.
    __shared__ float4 red[128];
    red[tid] = acc;
    __syncthreads();
    if (tid < 64) {
        float4 a = red[tid], c = red[tid + 64];
        a.x += c.x; a.y += c.y; a.z += c.z; a.w += c.w;
        red[tid] = a;
    }
    __syncthreads();
    if (tid < 32) {
        float4 a = red[tid], c = red[tid + 32];
        a.x += c.x; a.y += c.y; a.z += c.z; a.w += c.w;
        reinterpret_cast<float4*>(g_agg)[(long)n * 32 + tid] = a;
    }
}

// 16 nodes per block, 128 threads (thread = out feature). Unchanged.
__global__ __launch_bounds__(128) void node_kernel(
        const float* __restrict__ h,
        const float* __restrict__ node_norm,
        const float* __restrict__ h_bias,
        const float* __restrict__ loop_weight,
        const float* __restrict__ time_embed,
        const int* __restrict__ time_idx,
        float* __restrict__ out) {
    __shared__ float hsm[IN * 16];   // hsm[i*16 + nl]
    const int tid  = threadIdx.x;
    const int base = blockIdx.x * 16;

    for (int k = tid; k < 16 * IN; k += 128) {
        int nl = k >> 7;
        int i  = k & 127;
        hsm[i * 16 + nl] = h[(long)(base + nl) * IN + i];
    }
    __syncthreads();

    float acc[16];
#pragma unroll
    for (int nl = 0; nl < 16; ++nl) acc[nl] = 0.f;

    for (int i = 0; i < IN; ++i) {
        float w = loop_weight[(long)i * OUT + tid];
        const float4* hp = reinterpret_cast<const float4*>(&hsm[i * 16]);
#pragma unroll
        for (int q = 0; q < 4; ++q) {
            float4 hv = hp[q];
            acc[q * 4 + 0] = fmaf(hv.x, w, acc[q * 4 + 0]);
            acc[q * 4 + 1] = fmaf(hv.y, w, acc[q * 4 + 1]);
            acc[q * 4 + 2] = fmaf(hv.z, w, acc[q * 4 + 2]);
            acc[q * 4 + 3] = fmaf(hv.w, w, acc[q * 4 + 3]);
        }
    }

    float bias = h_bias[tid];
#pragma unroll
    for (int nl = 0; nl < 16; ++nl) {
        int n = base + nl;
        float v = g_agg[(long)n * OUT + tid] * node_norm[n] + bias + acc[nl];
        out[(long)n * OUT + tid] = fmaxf(v, 0.f);
        out[(long)N * OUT + (long)n * IN + tid] =
            time_embed[(long)time_idx[n] * IN + tid];
    }
}

extern "C" void kernel_launch(void* const* d_in, const int* in_sizes, int n_in,
                              void* d_out, int out_size, void* d_ws, size_t ws_size,
                              hipStream_t stream) {
    const float* h           = (const float*)d_in[0];
    const float* edge_norm   = (const float*)d_in[1];
    const float* node_norm   = (const float*)d_in[2];
    const float* weight      = (const float*)d_in[3];
    const float* h_bias      = (const float*)d_in[4];
    const float* loop_weight = (const float*)d_in[5];
    const float* time_embed  = (const float*)d_in[6];
    const int*   edge_src    = (const int*)d_in[7];
    const int*   edge_dst    = (const int*)d_in[8];
    const int*   edge_type   = (const int*)d_in[9];
    const int*   time_idx    = (const int*)d_in[10];
    float* out = (float*)d_out;

    zero_deg_kernel<<<(N + 255) / 256, 256, 0, stream>>>();
    count_kernel<<<(E + 255) / 256, 256, 0, stream>>>(edge_dst);
    scan_kernel<<<1, 1024, 0, stream>>>();
    scatter_kernel<<<(E + 255) / 256, 256, 0, stream>>>(
        edge_src, edge_dst, edge_type, edge_norm);

    agg_kernel<<<N, 128, 0, stream>>>(h, weight);

    node_kernel<<<N / 16, 128, 0, stream>>>(
        h, node_norm, h_bias, loop_weight, time_embed, time_idx, out);
}